// Round 1
// 232.390 us; speedup vs baseline: 1.0838x; 1.0838x over previous
//
#include <hip/hip_runtime.h>

#define BB 2
#define CC 1024
#define HH 16
#define TT 2048
#define SS 2048
#define LL 2048   // T == S
#define C2MASK 1442695.0f   // 1e6 * log2(e)
#define NT_TILES (SS / 64)

typedef unsigned short u16;
typedef unsigned int u32;
typedef __attribute__((ext_vector_type(8))) short short8;
typedef __attribute__((ext_vector_type(4))) float f32x4;
typedef __attribute__((ext_vector_type(4))) unsigned short us4;
typedef __attribute__((ext_vector_type(2))) unsigned int u32x2;

__device__ __forceinline__ u16 f2bf(float f) {
    union { float f; unsigned int i; } x; x.f = f;
    unsigned int r = x.i + 0x7FFFu + ((x.i >> 16) & 1u);
    return (u16)(r >> 16);
}
__device__ __forceinline__ float exp2_hw(float x) {
    float r;
    asm("v_exp_f32 %0, %1" : "=v"(r) : "v"(x));
    return r;
}
__device__ __forceinline__ float max3f(float a, float b, float c) {
    float r;
    asm("v_max3_f32 %0, %1, %2, %3" : "=v"(r) : "v"(a), "v"(b), "v"(c));
    return r;
}
__device__ __forceinline__ u32 cvtpk_bf16(float lo, float hi) {
    u32 r;
    asm("v_cvt_pk_bf16_f32 %0, %1, %2" : "=v"(r) : "v"(lo), "v"(hi));
    return r;
}
// direct global->LDS, 16B per lane; LDS dest = wave-uniform base + lane*16
__device__ __forceinline__ void gload_lds16(const u16* g, u16* l) {
    __builtin_amdgcn_global_load_lds(
        (const __attribute__((address_space(1))) unsigned int*)g,
        (__attribute__((address_space(3))) unsigned int*)l, 16, 0, 0);
}

// ---------- QKV projection GEMM (transpose fused into B staging) ----------
// Out[o][l] = sum_c W[o][c] * X[b][c][l] + bias[o]   (fp32 in, bf16 out)
// p=0: Q*(0.125*log2e)*tmask -> Qb [b][h][t][64]; p=1: K -> Kb; p=2: V -> Vb [b][o][s]
// blocks (0,0,z<2) additionally precompute sbias[b][s] (+ zrow) for attn.
__global__ __launch_bounds__(256) void qkv_gemm(
    const float* __restrict__ target, const float* __restrict__ source,
    const float* __restrict__ tmaskp, const float* __restrict__ smaskp,
    const float* __restrict__ Wq, const float* __restrict__ bq,
    const float* __restrict__ Wk, const float* __restrict__ bk,
    const float* __restrict__ Wv, const float* __restrict__ bv,
    u16* __restrict__ Qb, u16* __restrict__ Kb, u16* __restrict__ Vb,
    float* __restrict__ sbias, float* __restrict__ zrow)
{
    const int p = blockIdx.z >> 1;
    const int b = blockIdx.z & 1;

    // fused prep: additive s-mask bias (log2 domain) + zeros row for masked-t lanes
    if (blockIdx.x == 0 && blockIdx.y == 0 && p == 0) {
        const float* sm = smaskp + (size_t)b * SS;
        float* sb = sbias + (size_t)b * SS;
        for (int i = threadIdx.x; i < SS; i += 256) {
            sb[i] = (sm[i] > 0.5f) ? 0.0f : -C2MASK;
            if (b == 0) zrow[i] = 0.0f;
        }
    }

    const float* W    = (p == 0) ? Wq : (p == 1) ? Wk : Wv;
    const float* bias = (p == 0) ? bq : (p == 1) ? bk : bv;
    const float* X    = ((p == 0) ? target : source) + (size_t)b * CC * LL;

    const int m0 = blockIdx.y * 128;   // o
    const int n0 = blockIdx.x * 128;   // l (token)

    __shared__ __align__(16) u16 As[128 * 72];  // As[o_local][c_local]
    __shared__ __align__(16) u16 Bs[128 * 72];  // Bs[l_local][c_local]

    const int tid  = threadIdx.x;
    const int lane = tid & 63;
    const int wid  = tid >> 6;
    const int ln   = lane & 15;
    const int q    = lane >> 4;
    const int wm   = (wid >> 1) * 64;
    const int wn   = (wid & 1) * 64;

    f32x4 acc[4][4];
#pragma unroll
    for (int i = 0; i < 4; i++)
#pragma unroll
        for (int j = 0; j < 4; j++) acc[i][j] = (f32x4){0.f, 0.f, 0.f, 0.f};

    const int arow_s = tid >> 3;       // 0..31
    const int ach    = tid & 7;        // 8-elem chunk within 64-elem c-slab
    const int lp     = tid & 31;       // l-patch (4 l each)
    const int cp0    = tid >> 5;       // 0..7 (c-patch base)

    for (int k0 = 0; k0 < CC; k0 += 64) {
        __syncthreads();
        // --- stage A: W[o][c] fp32 -> bf16, row-major ---
#pragma unroll
        for (int i = 0; i < 4; i++) {
            const int row = arow_s + i * 32;
            const float* wp = W + (size_t)(m0 + row) * CC + k0 + ach * 8;
            f32x4 w0 = *(const f32x4*)wp;
            f32x4 w1 = *(const f32x4*)(wp + 4);
            short8 av;
#pragma unroll
            for (int j = 0; j < 4; j++) { av[j] = (short)f2bf(w0[j]); av[4 + j] = (short)f2bf(w1[j]); }
            *(short8*)(As + row * 72 + ach * 8) = av;
        }
        // --- stage B with transpose: X[c][l] fp32 -> Bs[l][c] bf16, 4x4 patches ---
#pragma unroll
        for (int i = 0; i < 2; i++) {
            const int cpi = cp0 + i * 8;    // c-patch 0..15 (4 c each)
            const float* xp = X + (size_t)(k0 + cpi * 4) * LL + n0 + lp * 4;
            f32x4 x0 = *(const f32x4*)(xp);
            f32x4 x1 = *(const f32x4*)(xp + LL);
            f32x4 x2 = *(const f32x4*)(xp + 2 * LL);
            f32x4 x3 = *(const f32x4*)(xp + 3 * LL);
#pragma unroll
            for (int u = 0; u < 4; u++) {
                us4 w;
                w[0] = f2bf(x0[u]); w[1] = f2bf(x1[u]);
                w[2] = f2bf(x2[u]); w[3] = f2bf(x3[u]);
                *(us4*)(Bs + (lp * 4 + u) * 72 + cpi * 4) = w;
            }
        }
        __syncthreads();

        short8 aF[4][2], bF[4][2];
#pragma unroll
        for (int mt = 0; mt < 4; mt++) {
            aF[mt][0] = *(const short8*)(As + (wm + mt*16 + ln) * 72 + q * 8);
            aF[mt][1] = *(const short8*)(As + (wm + mt*16 + ln) * 72 + 32 + q * 8);
        }
#pragma unroll
        for (int nt = 0; nt < 4; nt++) {
            bF[nt][0] = *(const short8*)(Bs + (wn + nt*16 + ln) * 72 + q * 8);
            bF[nt][1] = *(const short8*)(Bs + (wn + nt*16 + ln) * 72 + 32 + q * 8);
        }
#pragma unroll
        for (int mt = 0; mt < 4; mt++)
#pragma unroll
            for (int nt = 0; nt < 4; nt++) {
                acc[mt][nt] = __builtin_amdgcn_mfma_f32_16x16x32_bf16(aF[mt][0], bF[nt][0], acc[mt][nt], 0, 0, 0);
                acc[mt][nt] = __builtin_amdgcn_mfma_f32_16x16x32_bf16(aF[mt][1], bF[nt][1], acc[mt][nt], 0, 0, 0);
            }
    }

    // Q folds 1/sqrt(DH) * log2(e): softmax runs in log2 domain (exp2 HW op).
    // Q rows of masked-t tokens are zeroed (tmask is binary) so attn can select a
    // zeros bias row per lane and reproduce the reference's uniform softmax exactly.
    const float oscale = (p == 0) ? 0.18033688011112042f : 1.0f;
    // epilogue: D layout col = lane&15 (= l), row = q*4+reg (= o)
#pragma unroll
    for (int mt = 0; mt < 4; mt++) {
        const int o_base = m0 + wm + mt * 16 + q * 4;
        float bsf[4];
#pragma unroll
        for (int r = 0; r < 4; r++) bsf[r] = bias[o_base + r];
#pragma unroll
        for (int nt = 0; nt < 4; nt++) {
            const int l = n0 + wn + nt * 16 + ln;
            if (p == 2) {
#pragma unroll
                for (int r = 0; r < 4; r++)
                    Vb[((size_t)b * CC + o_base + r) * SS + l] = f2bf(acc[mt][nt][r] + bsf[r]);
            } else {
                const int h = o_base >> 6;
                const int d = o_base & 63;
                u16* dst = (p == 0) ? Qb : Kb;
                float sc2 = oscale;
                if (p == 0) sc2 = oscale * tmaskp[(size_t)b * TT + l];
                us4 pk;
#pragma unroll
                for (int r = 0; r < 4; r++) pk[r] = (u16)f2bf((acc[mt][nt][r] + bsf[r]) * sc2);
                *(us4*)(dst + ((size_t)(b * HH + h) * TT + l) * 64 + d) = pk;
            }
        }
    }
}

// ---------- flash attention ----------
// S^T = K·Q^T with s-mask bias folded into the MFMA C-operand; t-mask folded into
// Q (zeroed rows) + per-lane bias-pointer select. K/V double-buffered in LDS via
// global_load_lds with XOR-swizzled source (linear dest, swizzled reads): one
// barrier per s-tile, next tile's loads in flight across compute.
__global__ __launch_bounds__(256, 4) void attn_k(
    const u16* __restrict__ Qb, const u16* __restrict__ Kb, const u16* __restrict__ Vb,
    const float* __restrict__ tmask, const float* __restrict__ sbias,
    const float* __restrict__ zrow, float* __restrict__ out)
{
    __shared__ __align__(16) u16 Ks[2][64 * 64];   // [s_local][d], 16B-chunk col ^= (row&7)
    __shared__ __align__(16) u16 Vs[2][64 * 64];   // [d][s_local], same swizzle
    __shared__ __align__(16) u16 Ps[4][16 * 64];   // per-wave P^T [t_local][s_local], same swizzle

    const int tid  = threadIdx.x;
    const int wid  = tid >> 6;
    const int lane = tid & 63;
    const int ln   = lane & 15;
    const int q    = lane >> 4;

    // XCD-locality swizzle: all 32 t-tiles of one (b,h) share idx%8 -> same XCD L2
    const int idx   = blockIdx.x;
    const int xcd   = idx & 7;
    const int rest  = idx >> 3;
    const int ttile = rest & 31;
    const int bh    = (rest >> 5) * 8 + xcd;   // 0..31
    const int b     = bh >> 4;
    const int h     = bh & 15;
    const int t0    = ttile * 64 + wid * 16;

    const u16* Qp = Qb + (size_t)bh * TT * 64;
    const u16* Kp = Kb + (size_t)bh * SS * 64;
    const u16* Vp = Vb + ((size_t)b * CC + h * 64) * SS;

    // per-lane bias row: additive s-mask bias for kept t-rows, zeros for masked rows
    // (masked rows: Q==0 -> sc==0 -> P==1 for all s -> out = mean over ALL s = reference)
    const float tm = tmask[(size_t)b * TT + t0 + ln];
    const float* bp = (tm > 0.5f) ? (sbias + (size_t)b * SS) : zrow;

    // staging: 512 16B-chunks per 8KB tile; thread stages chunks tid and tid+256.
    // source pre-swizzled so linear LDS + swizzled read = identity (rule: both sides).
    const int r0  = tid >> 3;                 // row of chunk tid (row of tid+256 is r0+32)
    const int c0  = tid & 7;
    const int cs0 = c0 ^ (r0 & 7);            // (r0+32)&7 == r0&7, so same for chunk tid+256
    const u16* kg0 = Kp + (size_t)r0 * 64 + cs0 * 8;
    const u16* kg1 = Kp + (size_t)(r0 + 32) * 64 + cs0 * 8;
    const u16* vg0 = Vp + (size_t)r0 * SS + cs0 * 8;
    const u16* vg1 = Vp + (size_t)(r0 + 32) * SS + cs0 * 8;
    const int lw0 = wid * 512;                // u16 LDS base, chunks [wid*64, +64)
    const int lw1 = 2048 + wid * 512;         // chunks [256+wid*64, +64)

#define STAGE(buf, sn) do {                                         \
        gload_lds16(kg0 + (size_t)(sn) * 64, &Ks[buf][lw0]);        \
        gload_lds16(kg1 + (size_t)(sn) * 64, &Ks[buf][lw1]);        \
        gload_lds16(vg0 + (sn), &Vs[buf][lw0]);                     \
        gload_lds16(vg1 + (sn), &Vs[buf][lw1]);                     \
    } while (0)

    // Q as B-operand: B[n=t=ln][k=d chunk q*8]
    short8 qB0 = *(const short8*)(Qp + (size_t)(t0 + ln) * 64 + q * 8);
    short8 qB1 = *(const short8*)(Qp + (size_t)(t0 + ln) * 64 + 32 + q * 8);

    float mR = -3.0e38f, lR = 0.f;
    f32x4 oA[4];   // PV accum: D[row=d_local=q*4+r (+dt*16)][col=t=ln]
#pragma unroll
    for (int dt = 0; dt < 4; dt++) oA[dt] = (f32x4){0.f, 0.f, 0.f, 0.f};

    // swizzled fragment-read offsets (u16): rows read by this lane all have row&7 == ln&7
    const int sx0 = ((q ^ (ln & 7)) << 3);
    const int sx1 = (((q + 4) ^ (ln & 7)) << 3);

    u16* pw = Ps[wid];

    STAGE(0, 0);   // prologue

    int cur = 0;
#pragma unroll 2
    for (int it = 0; it < NT_TILES; ++it) {
        const int s0 = it * 64;
        __syncthreads();                       // drains prev loads (vmcnt) + frag reads (lgkm)
        if (it + 1 < NT_TILES) STAGE(cur ^ 1, s0 + 64);   // next tile in flight over compute

        const u16* KsB = Ks[cur];
        const u16* VsB = Vs[cur];

        // S^T tile (log2 domain): row = s_local = q*4+r (+nt*16), col = t = ln.
        // s-mask bias rides in the first MFMA's C operand -> zero mask VALU.
        f32x4 sc[4];
#pragma unroll
        for (int nt = 0; nt < 4; nt++) {
            const u16* kr = KsB + (nt * 16 + ln) * 64;
            short8 k0 = *(const short8*)(kr + sx0);
            short8 k1 = *(const short8*)(kr + sx1);
            f32x4 bias = *(const f32x4*)(bp + s0 + nt * 16 + q * 4);
            sc[nt] = __builtin_amdgcn_mfma_f32_16x16x32_bf16(k0, qB0, bias, 0, 0, 0);
            sc[nt] = __builtin_amdgcn_mfma_f32_16x16x32_bf16(k1, qB1, sc[nt], 0, 0, 0);
        }

        // row-max over 64 s: in-lane (v_max3) + xor across the 4 q-groups
        float m4[4];
#pragma unroll
        for (int nt = 0; nt < 4; nt++)
            m4[nt] = fmaxf(max3f(sc[nt][0], sc[nt][1], sc[nt][2]), sc[nt][3]);
        float m_ = fmaxf(max3f(m4[0], m4[1], m4[2]), m4[3]);
        m_ = fmaxf(m_, __shfl_xor(m_, 16, 64));
        m_ = fmaxf(m_, __shfl_xor(m_, 32, 64));

        // defer-max (THR=8, log2 domain): skip rescale unless some row grew > 2^8
        if (!__all(m_ - mR <= 8.0f)) {
            const float mN = fmaxf(mR, m_);
            const float al = exp2_hw(mR - mN);
            lR *= al;
#pragma unroll
            for (int dt = 0; dt < 4; dt++) oA[dt] *= al;
            mR = mN;
        }

        float s4[4];
#pragma unroll
        for (int nt = 0; nt < 4; nt++) {
#pragma unroll
            for (int r = 0; r < 4; r++) sc[nt][r] = exp2_hw(sc[nt][r] - mR);
            s4[nt] = (sc[nt][0] + sc[nt][1]) + (sc[nt][2] + sc[nt][3]);
        }
        float s_ = (s4[0] + s4[1]) + (s4[2] + s4[3]);
        s_ += __shfl_xor(s_, 16, 64);
        s_ += __shfl_xor(s_, 32, 64);
        lR += s_;

        // P^T -> per-wave LDS (v_cvt_pk packs; swizzled 8B writes)
#pragma unroll
        for (int nt = 0; nt < 4; nt++) {
            u32x2 w;
            w[0] = cvtpk_bf16(sc[nt][0], sc[nt][1]);
            w[1] = cvtpk_bf16(sc[nt][2], sc[nt][3]);
            const int chunk = (nt << 1) | (q >> 1);
            *(u32x2*)(pw + ln * 64 + ((chunk ^ (ln & 7)) << 3) + ((q & 1) << 2)) = w;
        }
        // P as B-operand: B[n=t=ln][k=s chunk q*8]
        short8 pB0 = *(const short8*)(pw + ln * 64 + sx0);
        short8 pB1 = *(const short8*)(pw + ln * 64 + sx1);
#pragma unroll
        for (int dt = 0; dt < 4; dt++) {
            const u16* vr = VsB + (dt * 16 + ln) * 64;
            short8 v0 = *(const short8*)(vr + sx0);
            short8 v1 = *(const short8*)(vr + sx1);
            oA[dt] = __builtin_amdgcn_mfma_f32_16x16x32_bf16(v0, pB0, oA[dt], 0, 0, 0);
            oA[dt] = __builtin_amdgcn_mfma_f32_16x16x32_bf16(v1, pB1, oA[dt], 0, 0, 0);
        }
        cur ^= 1;
    }
#undef STAGE

    const float inv = 1.0f / lR;
    // D: row = d = dt*16 + q*4 + r, col = t = t0 + ln
#pragma unroll
    for (int dt = 0; dt < 4; dt++)
#pragma unroll
        for (int r = 0; r < 4; r++)
            out[((size_t)b * CC + h * 64 + dt * 16 + q * 4 + r) * TT + t0 + ln] =
                oA[dt][r] * inv;
}

extern "C" void kernel_launch(void* const* d_in, const int* in_sizes, int n_in,
                              void* d_out, int out_size, void* d_ws, size_t ws_size,
                              hipStream_t stream)
{
    const float* target = (const float*)d_in[0];
    const float* source = (const float*)d_in[1];
    const float* tmask  = (const float*)d_in[2];
    const float* smask  = (const float*)d_in[3];
    const float* Wq = (const float*)d_in[4];
    const float* bq = (const float*)d_in[5];
    const float* Wk = (const float*)d_in[6];
    const float* bk = (const float*)d_in[7];
    const float* Wv = (const float*)d_in[8];
    const float* bv = (const float*)d_in[9];

    u16* ws = (u16*)d_ws;
    const size_t N1 = (size_t)BB * CC * TT;   // 4,194,304 elements (8 MB bf16)
    u16* Qb = ws;
    u16* Kb = ws + N1;
    u16* Vb = ws + 2 * N1;                    // 24 MB bf16
    float* sbias = (float*)(ws + 3 * N1);     // [2][2048] f32 additive s-mask bias
    float* zrow  = sbias + 2 * SS;            // [2048] zeros (bias for masked-t rows)

    qkv_gemm<<<dim3(TT/128, CC/128, 6), dim3(256, 1, 1), 0, stream>>>(
        target, source, tmask, smask, Wq, bq, Wk, bk, Wv, bv, Qb, Kb, Vb, sbias, zrow);
    attn_k<<<dim3(BB*HH*(TT/64), 1, 1), dim3(256, 1, 1), 0, stream>>>(
        Qb, Kb, Vb, tmask, sbias, zrow, (float*)d_out);
}

// Round 2
// 205.348 us; speedup vs baseline: 1.2265x; 1.1317x over previous
//
#include <hip/hip_runtime.h>

#define BB 2
#define CC 1024
#define HH 16
#define TT 2048
#define SS 2048
#define LL 2048   // T == S
#define C2MASK 1442695.0f   // 1e6 * log2(e)
#define NT_TILES (SS / 64)

typedef unsigned short u16;
typedef unsigned int u32;
typedef __attribute__((ext_vector_type(8))) short short8;
typedef __attribute__((ext_vector_type(4))) float f32x4;
typedef __attribute__((ext_vector_type(4))) unsigned short us4;
typedef __attribute__((ext_vector_type(2))) unsigned int u32x2;
typedef __attribute__((ext_vector_type(4))) unsigned int u32x4;

__device__ __forceinline__ u16 f2bf(float f) {
    union { float f; unsigned int i; } x; x.f = f;
    unsigned int r = x.i + 0x7FFFu + ((x.i >> 16) & 1u);
    return (u16)(r >> 16);
}
__device__ __forceinline__ float exp2_hw(float x) {
    float r;
    asm("v_exp_f32 %0, %1" : "=v"(r) : "v"(x));
    return r;
}
__device__ __forceinline__ float max3f(float a, float b, float c) {
    float r;
    asm("v_max3_f32 %0, %1, %2, %3" : "=v"(r) : "v"(a), "v"(b), "v"(c));
    return r;
}
__device__ __forceinline__ u32 cvtpk_bf16(float lo, float hi) {
    u32 r;
    asm("v_cvt_pk_bf16_f32 %0, %1, %2" : "=v"(r) : "v"(lo), "v"(hi));
    return r;
}
// direct global->LDS, 16B per lane; LDS dest = wave-uniform base + lane*16
__device__ __forceinline__ void gload_lds16(const u16* g, u16* l) {
    __builtin_amdgcn_global_load_lds(
        (const __attribute__((address_space(1))) unsigned int*)g,
        (__attribute__((address_space(3))) unsigned int*)l, 16, 0, 0);
}

// ---------- prep: one-shot fp32->bf16 conversion (memory-bound) ----------
// blocks [0,2048): transpose-convert X [b][c][l] -> Xt [b][l][c] bf16 (64x64 tiles)
// blocks [2048,3584): convert Wq|Wk|Wv -> Wb bf16 row-major; first 2 also sbias/zrow
__global__ __launch_bounds__(256) void prep(
    const float* __restrict__ target, const float* __restrict__ source,
    const float* __restrict__ smaskp,
    const float* __restrict__ Wq, const float* __restrict__ Wk, const float* __restrict__ Wv,
    u16* __restrict__ Wb, u16* __restrict__ Tt, u16* __restrict__ St,
    float* __restrict__ sbias, float* __restrict__ zrow)
{
    __shared__ float xs[64][65];   // +1 pad: 2-way (free) banks both phases
    const int tid = threadIdx.x;
    const int bid = blockIdx.x;

    if (bid < 2048) {
        const int img  = bid >> 9;          // 0,1: target b=0,1; 2,3: source b=0,1
        const int tile = bid & 511;
        const int ct = tile >> 5, lt = tile & 31;
        const int c0 = ct * 64, l0 = lt * 64;
        const float* src = ((img < 2) ? target : source) + (size_t)(img & 1) * CC * LL;
        u16* dst = ((img < 2) ? Tt : St) + (size_t)(img & 1) * LL * CC;

        // load 64c x 64l tile, coalesced along l
        const int i = tid >> 2, seg = (tid & 3) * 16;
        const float* g = src + (size_t)(c0 + i) * LL + l0 + seg;
        f32x4 a0 = *(const f32x4*)g;
        f32x4 a1 = *(const f32x4*)(g + 4);
        f32x4 a2 = *(const f32x4*)(g + 8);
        f32x4 a3 = *(const f32x4*)(g + 12);
#pragma unroll
        for (int j = 0; j < 4; j++) {
            xs[i][seg + j]      = a0[j];
            xs[i][seg + 4 + j]  = a1[j];
            xs[i][seg + 8 + j]  = a2[j];
            xs[i][seg + 12 + j] = a3[j];
        }
        __syncthreads();

        // write 64l x 64c bf16, coalesced along c
        const int l = tid >> 2, cseg = (tid & 3) * 16;
        float f[16];
#pragma unroll
        for (int j = 0; j < 16; j++) f[j] = xs[cseg + j][l];
        u32x4 o0, o1;
#pragma unroll
        for (int k = 0; k < 4; k++) {
            o0[k] = cvtpk_bf16(f[2 * k], f[2 * k + 1]);
            o1[k] = cvtpk_bf16(f[8 + 2 * k], f[9 + 2 * k]);
        }
        u16* d = dst + (size_t)(l0 + l) * CC + c0 + cseg;
        *(u32x4*)d = o0;
        *(u32x4*)(d + 8) = o1;
    } else {
        const int wblk = bid - 2048;              // 0..1535; 512 blocks per matrix
        const size_t idx = (size_t)wblk * 2048 + tid * 8;
        const int m = (int)(idx >> 20);
        const size_t rem = idx & 1048575;
        const float* srcp = ((m == 0) ? Wq : (m == 1) ? Wk : Wv) + rem;
        f32x4 a = *(const f32x4*)srcp;
        f32x4 c = *(const f32x4*)(srcp + 4);
        u32x4 o;
        o[0] = cvtpk_bf16(a[0], a[1]); o[1] = cvtpk_bf16(a[2], a[3]);
        o[2] = cvtpk_bf16(c[0], c[1]); o[3] = cvtpk_bf16(c[2], c[3]);
        *(u32x4*)(Wb + ((size_t)m << 20) + rem) = o;

        if (wblk < 2) {   // fused: s-mask additive bias (log2 domain) + zeros row
            const int b = wblk;
            const float* sm = smaskp + (size_t)b * SS;
            float* sb = sbias + (size_t)b * SS;
            for (int s = tid; s < SS; s += 256) {
                sb[s] = (sm[s] > 0.5f) ? 0.0f : -C2MASK;
                if (b == 0) zrow[s] = 0.0f;
            }
        }
    }
}

// ---------- QKV projection GEMM: m97 structure, pure bf16 ----------
// A = Wb[p] [o][c] row-major, B = Xt [l][c] row-major (B^T input).
// global_load_lds staging with inverse-swizzled source; swizzled conflict-free reads.
// p=0: Q*(0.125*log2e)*tmask -> Qb [b][h][t][64]; p=1: K -> Kb; p=2: V -> Vb [b][o][s]
__global__ __launch_bounds__(256) void qkv_gemm(
    const u16* __restrict__ Wb, const u16* __restrict__ Tt, const u16* __restrict__ St,
    const float* __restrict__ bq, const float* __restrict__ bk, const float* __restrict__ bv,
    const float* __restrict__ tmaskp,
    u16* __restrict__ Qb, u16* __restrict__ Kb, u16* __restrict__ Vb)
{
    __shared__ __align__(16) u16 As[128 * 64];   // [o_local][c], chunk col ^= (row&7)
    __shared__ __align__(16) u16 Bs[128 * 64];   // [l_local][c], same swizzle

    const int p = blockIdx.z >> 1;
    const int b = blockIdx.z & 1;
    const int m0 = blockIdx.y * 128;   // o
    const int n0 = blockIdx.x * 128;   // l

    const u16* A  = Wb + ((size_t)p << 20) + (size_t)m0 * CC;
    const u16* Bx = ((p == 0) ? Tt : St) + (size_t)b * LL * CC + (size_t)n0 * CC;
    const float* bias = (p == 0) ? bq : (p == 1) ? bk : bv;

    const int tid  = threadIdx.x;
    const int lane = tid & 63;
    const int wid  = tid >> 6;
    const int ln   = lane & 15;
    const int q    = lane >> 4;
    const int wm   = (wid >> 1) * 64;
    const int wn   = (wid & 1) * 64;

    // staging: thread stages chunk (row=tid>>3, col=tid&7) + 3 more rows at +32
    const int r0 = tid >> 3;
    const int cs = (tid & 7) ^ (r0 & 7);        // inverse swizzle on SOURCE
    const u16* ag = A  + (size_t)r0 * CC + cs * 8;
    const u16* bg = Bx + (size_t)r0 * CC + cs * 8;
    const int lb = wid * 512;                    // wave's linear LDS chunk base (u16)

    f32x4 acc[4][4];
#pragma unroll
    for (int i = 0; i < 4; i++)
#pragma unroll
        for (int j = 0; j < 4; j++) acc[i][j] = (f32x4){0.f, 0.f, 0.f, 0.f};

    // swizzled fragment-read offsets: rows read by a lane all have row&7 == ln&7
    const int sx0 = ((q ^ (ln & 7)) << 3);
    const int sx1 = (((q + 4) ^ (ln & 7)) << 3);

    for (int k0 = 0; k0 < CC; k0 += 64) {
        __syncthreads();
#pragma unroll
        for (int i = 0; i < 4; i++) {
            gload_lds16(ag + (size_t)i * 32 * CC + k0, &As[lb + i * 2048]);
            gload_lds16(bg + (size_t)i * 32 * CC + k0, &Bs[lb + i * 2048]);
        }
        __syncthreads();

        short8 aF[4][2], bF[4][2];
#pragma unroll
        for (int mt = 0; mt < 4; mt++) {
            const u16* ar = As + (wm + mt * 16 + ln) * 64;
            aF[mt][0] = *(const short8*)(ar + sx0);
            aF[mt][1] = *(const short8*)(ar + sx1);
        }
#pragma unroll
        for (int nt = 0; nt < 4; nt++) {
            const u16* br = Bs + (wn + nt * 16 + ln) * 64;
            bF[nt][0] = *(const short8*)(br + sx0);
            bF[nt][1] = *(const short8*)(br + sx1);
        }
#pragma unroll
        for (int mt = 0; mt < 4; mt++)
#pragma unroll
            for (int nt = 0; nt < 4; nt++) {
                acc[mt][nt] = __builtin_amdgcn_mfma_f32_16x16x32_bf16(aF[mt][0], bF[nt][0], acc[mt][nt], 0, 0, 0);
                acc[mt][nt] = __builtin_amdgcn_mfma_f32_16x16x32_bf16(aF[mt][1], bF[nt][1], acc[mt][nt], 0, 0, 0);
            }
    }

    // Q folds 1/sqrt(DH)*log2e and tmask (zeroed rows -> uniform softmax in attn)
    const float oscale = (p == 0) ? 0.18033688011112042f : 1.0f;
    // D layout: col = lane&15 (= l), row = q*4+reg (= o)
#pragma unroll
    for (int mt = 0; mt < 4; mt++) {
        const int o_base = m0 + wm + mt * 16 + q * 4;
        float bsf[4];
#pragma unroll
        for (int r = 0; r < 4; r++) bsf[r] = bias[o_base + r];
#pragma unroll
        for (int nt = 0; nt < 4; nt++) {
            const int l = n0 + wn + nt * 16 + ln;
            if (p == 2) {
#pragma unroll
                for (int r = 0; r < 4; r++)
                    Vb[((size_t)b * CC + o_base + r) * SS + l] = f2bf(acc[mt][nt][r] + bsf[r]);
            } else {
                const int h = o_base >> 6;
                const int d = o_base & 63;
                u16* dst = (p == 0) ? Qb : Kb;
                float sc2 = oscale;
                if (p == 0) sc2 = oscale * tmaskp[(size_t)b * TT + l];
                us4 pk;
#pragma unroll
                for (int r = 0; r < 4; r++) pk[r] = (u16)f2bf((acc[mt][nt][r] + bsf[r]) * sc2);
                *(us4*)(dst + ((size_t)(b * HH + h) * TT + l) * 64 + d) = pk;
            }
        }
    }
}

// ---------- flash attention (unchanged from round 1) ----------
__global__ __launch_bounds__(256, 4) void attn_k(
    const u16* __restrict__ Qb, const u16* __restrict__ Kb, const u16* __restrict__ Vb,
    const float* __restrict__ tmask, const float* __restrict__ sbias,
    const float* __restrict__ zrow, float* __restrict__ out)
{
    __shared__ __align__(16) u16 Ks[2][64 * 64];   // [s_local][d], 16B-chunk col ^= (row&7)
    __shared__ __align__(16) u16 Vs[2][64 * 64];   // [d][s_local], same swizzle
    __shared__ __align__(16) u16 Ps[4][16 * 64];   // per-wave P^T [t_local][s_local]

    const int tid  = threadIdx.x;
    const int wid  = tid >> 6;
    const int lane = tid & 63;
    const int ln   = lane & 15;
    const int q    = lane >> 4;

    const int idx   = blockIdx.x;
    const int xcd   = idx & 7;
    const int rest  = idx >> 3;
    const int ttile = rest & 31;
    const int bh    = (rest >> 5) * 8 + xcd;   // 0..31
    const int b     = bh >> 4;
    const int h     = bh & 15;
    const int t0    = ttile * 64 + wid * 16;

    const u16* Qp = Qb + (size_t)bh * TT * 64;
    const u16* Kp = Kb + (size_t)bh * SS * 64;
    const u16* Vp = Vb + ((size_t)b * CC + h * 64) * SS;

    const float tm = tmask[(size_t)b * TT + t0 + ln];
    const float* bp = (tm > 0.5f) ? (sbias + (size_t)b * SS) : zrow;

    const int r0  = tid >> 3;
    const int c0  = tid & 7;
    const int cs0 = c0 ^ (r0 & 7);
    const u16* kg0 = Kp + (size_t)r0 * 64 + cs0 * 8;
    const u16* kg1 = Kp + (size_t)(r0 + 32) * 64 + cs0 * 8;
    const u16* vg0 = Vp + (size_t)r0 * SS + cs0 * 8;
    const u16* vg1 = Vp + (size_t)(r0 + 32) * SS + cs0 * 8;
    const int lw0 = wid * 512;
    const int lw1 = 2048 + wid * 512;

#define STAGE(buf, sn) do {                                         \
        gload_lds16(kg0 + (size_t)(sn) * 64, &Ks[buf][lw0]);        \
        gload_lds16(kg1 + (size_t)(sn) * 64, &Ks[buf][lw1]);        \
        gload_lds16(vg0 + (sn), &Vs[buf][lw0]);                     \
        gload_lds16(vg1 + (sn), &Vs[buf][lw1]);                     \
    } while (0)

    short8 qB0 = *(const short8*)(Qp + (size_t)(t0 + ln) * 64 + q * 8);
    short8 qB1 = *(const short8*)(Qp + (size_t)(t0 + ln) * 64 + 32 + q * 8);

    float mR = -3.0e38f, lR = 0.f;
    f32x4 oA[4];
#pragma unroll
    for (int dt = 0; dt < 4; dt++) oA[dt] = (f32x4){0.f, 0.f, 0.f, 0.f};

    const int sx0 = ((q ^ (ln & 7)) << 3);
    const int sx1 = (((q + 4) ^ (ln & 7)) << 3);

    u16* pw = Ps[wid];

    STAGE(0, 0);

    int cur = 0;
#pragma unroll 2
    for (int it = 0; it < NT_TILES; ++it) {
        const int s0 = it * 64;
        __syncthreads();
        if (it + 1 < NT_TILES) STAGE(cur ^ 1, s0 + 64);

        const u16* KsB = Ks[cur];
        const u16* VsB = Vs[cur];

        f32x4 sc[4];
#pragma unroll
        for (int nt = 0; nt < 4; nt++) {
            const u16* kr = KsB + (nt * 16 + ln) * 64;
            short8 k0 = *(const short8*)(kr + sx0);
            short8 k1 = *(const short8*)(kr + sx1);
            f32x4 bias = *(const f32x4*)(bp + s0 + nt * 16 + q * 4);
            sc[nt] = __builtin_amdgcn_mfma_f32_16x16x32_bf16(k0, qB0, bias, 0, 0, 0);
            sc[nt] = __builtin_amdgcn_mfma_f32_16x16x32_bf16(k1, qB1, sc[nt], 0, 0, 0);
        }

        float m4[4];
#pragma unroll
        for (int nt = 0; nt < 4; nt++)
            m4[nt] = fmaxf(max3f(sc[nt][0], sc[nt][1], sc[nt][2]), sc[nt][3]);
        float m_ = fmaxf(max3f(m4[0], m4[1], m4[2]), m4[3]);
        m_ = fmaxf(m_, __shfl_xor(m_, 16, 64));
        m_ = fmaxf(m_, __shfl_xor(m_, 32, 64));

        if (!__all(m_ - mR <= 8.0f)) {
            const float mN = fmaxf(mR, m_);
            const float al = exp2_hw(mR - mN);
            lR *= al;
#pragma unroll
            for (int dt = 0; dt < 4; dt++) oA[dt] *= al;
            mR = mN;
        }

        float s4[4];
#pragma unroll
        for (int nt = 0; nt < 4; nt++) {
#pragma unroll
            for (int r = 0; r < 4; r++) sc[nt][r] = exp2_hw(sc[nt][r] - mR);
            s4[nt] = (sc[nt][0] + sc[nt][1]) + (sc[nt][2] + sc[nt][3]);
        }
        float s_ = (s4[0] + s4[1]) + (s4[2] + s4[3]);
        s_ += __shfl_xor(s_, 16, 64);
        s_ += __shfl_xor(s_, 32, 64);
        lR += s_;

#pragma unroll
        for (int nt = 0; nt < 4; nt++) {
            u32x2 w;
            w[0] = cvtpk_bf16(sc[nt][0], sc[nt][1]);
            w[1] = cvtpk_bf16(sc[nt][2], sc[nt][3]);
            const int chunk = (nt << 1) | (q >> 1);
            *(u32x2*)(pw + ln * 64 + ((chunk ^ (ln & 7)) << 3) + ((q & 1) << 2)) = w;
        }
        short8 pB0 = *(const short8*)(pw + ln * 64 + sx0);
        short8 pB1 = *(const short8*)(pw + ln * 64 + sx1);
#pragma unroll
        for (int dt = 0; dt < 4; dt++) {
            const u16* vr = VsB + (dt * 16 + ln) * 64;
            short8 v0 = *(const short8*)(vr + sx0);
            short8 v1 = *(const short8*)(vr + sx1);
            oA[dt] = __builtin_amdgcn_mfma_f32_16x16x32_bf16(v0, pB0, oA[dt], 0, 0, 0);
            oA[dt] = __builtin_amdgcn_mfma_f32_16x16x32_bf16(v1, pB1, oA[dt], 0, 0, 0);
        }
        cur ^= 1;
    }
#undef STAGE

    const float inv = 1.0f / lR;
#pragma unroll
    for (int dt = 0; dt < 4; dt++)
#pragma unroll
        for (int r = 0; r < 4; r++)
            out[((size_t)b * CC + h * 64 + dt * 16 + q * 4 + r) * TT + t0 + ln] =
                oA[dt][r] * inv;
}

extern "C" void kernel_launch(void* const* d_in, const int* in_sizes, int n_in,
                              void* d_out, int out_size, void* d_ws, size_t ws_size,
                              hipStream_t stream)
{
    const float* target = (const float*)d_in[0];
    const float* source = (const float*)d_in[1];
    const float* tmask  = (const float*)d_in[2];
    const float* smask  = (const float*)d_in[3];
    const float* Wq = (const float*)d_in[4];
    const float* bq = (const float*)d_in[5];
    const float* Wk = (const float*)d_in[6];
    const float* bk = (const float*)d_in[7];
    const float* Wv = (const float*)d_in[8];
    const float* bv = (const float*)d_in[9];

    u16* ws = (u16*)d_ws;
    const size_t N1 = (size_t)BB * CC * TT;   // 4,194,304 elements (8 MB bf16)
    u16* Qb = ws;
    u16* Kb = ws + N1;
    u16* Vb = ws + 2 * N1;                    // 24 MB bf16
    float* sbias = (float*)(ws + 3 * N1);     // [2][2048] f32
    float* zrow  = sbias + 2 * SS;            // [2048] f32
    u16* Wb = (u16*)(zrow + SS);              // [3][1024][1024] bf16, 6 MB
    u16* Tt = Wb + 3u * 1048576u;             // [2][2048][1024] bf16, 8 MB
    u16* St = Tt + (size_t)BB * LL * CC;      // [2][2048][1024] bf16, 8 MB

    prep<<<dim3(3584, 1, 1), dim3(256, 1, 1), 0, stream>>>(
        target, source, smask, Wq, Wk, Wv, Wb, Tt, St, sbias, zrow);
    qkv_gemm<<<dim3(TT/128, CC/128, 6), dim3(256, 1, 1), 0, stream>>>(
        Wb, Tt, St, bq, bk, bv, tmask, Qb, Kb, Vb);
    attn_k<<<dim3(BB*HH*(TT/64), 1, 1), dim3(256, 1, 1), 0, stream>>>(
        Qb, Kb, Vb, tmask, sbias, zrow, (float*)d_out);
}

// Round 3
// 200.260 us; speedup vs baseline: 1.2577x; 1.0254x over previous
//
#include <hip/hip_runtime.h>

#define BB 2
#define CC 1024
#define HH 16
#define TT 2048
#define SS 2048
#define LL 2048   // T == S
#define C2MASK 1442695.0f   // 1e6 * log2(e)
#define NT_TILES (SS / 64)

typedef unsigned short u16;
typedef unsigned int u32;
typedef __attribute__((ext_vector_type(8))) short short8;
typedef __attribute__((ext_vector_type(4))) float f32x4;
typedef __attribute__((ext_vector_type(4))) unsigned short us4;
typedef __attribute__((ext_vector_type(2))) unsigned int u32x2;
typedef __attribute__((ext_vector_type(4))) unsigned int u32x4;

__device__ __forceinline__ u16 f2bf(float f) {
    union { float f; unsigned int i; } x; x.f = f;
    unsigned int r = x.i + 0x7FFFu + ((x.i >> 16) & 1u);
    return (u16)(r >> 16);
}
__device__ __forceinline__ float exp2_hw(float x) {
    float r;
    asm("v_exp_f32 %0, %1" : "=v"(r) : "v"(x));
    return r;
}
__device__ __forceinline__ float max3f(float a, float b, float c) {
    float r;
    asm("v_max3_f32 %0, %1, %2, %3" : "=v"(r) : "v"(a), "v"(b), "v"(c));
    return r;
}
__device__ __forceinline__ u32 cvtpk_bf16(float lo, float hi) {
    u32 r;
    asm("v_cvt_pk_bf16_f32 %0, %1, %2" : "=v"(r) : "v"(lo), "v"(hi));
    return r;
}
// direct global->LDS, 16B per lane; LDS dest = wave-uniform base + lane*16
__device__ __forceinline__ void gload_lds16(const u16* g, u16* l) {
    __builtin_amdgcn_global_load_lds(
        (const __attribute__((address_space(1))) unsigned int*)g,
        (__attribute__((address_space(3))) unsigned int*)l, 16, 0, 0);
}

// ---------- prep: one-shot fp32->bf16 conversion (memory-bound) ----------
// blocks [0,2048): transpose-convert X [b][c][l] -> Xt [b][l][c] bf16 (64x64 tiles)
// blocks [2048,3584): convert Wq|Wk|Wv -> Wb bf16 row-major; first 2 also sbias/zrow
__global__ __launch_bounds__(256) void prep(
    const float* __restrict__ target, const float* __restrict__ source,
    const float* __restrict__ smaskp,
    const float* __restrict__ Wq, const float* __restrict__ Wk, const float* __restrict__ Wv,
    u16* __restrict__ Wb, u16* __restrict__ Tt, u16* __restrict__ St,
    float* __restrict__ sbias, float* __restrict__ zrow)
{
    __shared__ float xs[64][65];   // +1 pad: 2-way (free) banks both phases
    const int tid = threadIdx.x;
    const int bid = blockIdx.x;

    if (bid < 2048) {
        const int img  = bid >> 9;          // 0,1: target b=0,1; 2,3: source b=0,1
        const int tile = bid & 511;
        const int ct = tile >> 5, lt = tile & 31;
        const int c0 = ct * 64, l0 = lt * 64;
        const float* src = ((img < 2) ? target : source) + (size_t)(img & 1) * CC * LL;
        u16* dst = ((img < 2) ? Tt : St) + (size_t)(img & 1) * LL * CC;

        // load 64c x 64l tile, coalesced along l
        const int i = tid >> 2, seg = (tid & 3) * 16;
        const float* g = src + (size_t)(c0 + i) * LL + l0 + seg;
        f32x4 a0 = *(const f32x4*)g;
        f32x4 a1 = *(const f32x4*)(g + 4);
        f32x4 a2 = *(const f32x4*)(g + 8);
        f32x4 a3 = *(const f32x4*)(g + 12);
#pragma unroll
        for (int j = 0; j < 4; j++) {
            xs[i][seg + j]      = a0[j];
            xs[i][seg + 4 + j]  = a1[j];
            xs[i][seg + 8 + j]  = a2[j];
            xs[i][seg + 12 + j] = a3[j];
        }
        __syncthreads();

        // write 64l x 64c bf16, coalesced along c
        const int l = tid >> 2, cseg = (tid & 3) * 16;
        float f[16];
#pragma unroll
        for (int j = 0; j < 16; j++) f[j] = xs[cseg + j][l];
        u32x4 o0, o1;
#pragma unroll
        for (int k = 0; k < 4; k++) {
            o0[k] = cvtpk_bf16(f[2 * k], f[2 * k + 1]);
            o1[k] = cvtpk_bf16(f[8 + 2 * k], f[9 + 2 * k]);
        }
        u16* d = dst + (size_t)(l0 + l) * CC + c0 + cseg;
        *(u32x4*)d = o0;
        *(u32x4*)(d + 8) = o1;
    } else {
        const int wblk = bid - 2048;              // 0..1535; 512 blocks per matrix
        const size_t idx = (size_t)wblk * 2048 + tid * 8;
        const int m = (int)(idx >> 20);
        const size_t rem = idx & 1048575;
        const float* srcp = ((m == 0) ? Wq : (m == 1) ? Wk : Wv) + rem;
        f32x4 a = *(const f32x4*)srcp;
        f32x4 c = *(const f32x4*)(srcp + 4);
        u32x4 o;
        o[0] = cvtpk_bf16(a[0], a[1]); o[1] = cvtpk_bf16(a[2], a[3]);
        o[2] = cvtpk_bf16(c[0], c[1]); o[3] = cvtpk_bf16(c[2], c[3]);
        *(u32x4*)(Wb + ((size_t)m << 20) + rem) = o;

        if (wblk < 2) {   // fused: s-mask additive bias (log2 domain) + zeros row
            const int b = wblk;
            const float* sm = smaskp + (size_t)b * SS;
            float* sb = sbias + (size_t)b * SS;
            for (int s = tid; s < SS; s += 256) {
                sb[s] = (sm[s] > 0.5f) ? 0.0f : -C2MASK;
                if (b == 0) zrow[s] = 0.0f;
            }
        }
    }
}

// ---------- QKV projection GEMM: 2-phase double-buffered, BK=32, pure bf16 ----------
// A = Wb[p] [o][c] row-major, B = Xt [l][c] row-major (B^T input).
// Single barrier per k-step; next k-tile's global_load_lds fly across compute.
// LDS chunk permutation: slot = p*8 + ((4b+c)^(p&7)), row=2p+b  -> conflict-spread
// fragment reads; writes remain wave-linear (gload_lds-legal).
// p=0: Q*(0.125*log2e)*tmask -> Qb [b][h][t][64]; p=1: K -> Kb; p=2: V -> Vb [b][o][s]
__global__ __launch_bounds__(256) void qkv_gemm(
    const u16* __restrict__ Wb, const u16* __restrict__ Tt, const u16* __restrict__ St,
    const float* __restrict__ bq, const float* __restrict__ bk, const float* __restrict__ bv,
    const float* __restrict__ tmaskp,
    u16* __restrict__ Qb, u16* __restrict__ Kb, u16* __restrict__ Vb)
{
    __shared__ __align__(16) u16 As[2][4096];   // 128 rows x 32 k, permuted chunks
    __shared__ __align__(16) u16 Bs[2][4096];

    const int p = blockIdx.z >> 1;
    const int b = blockIdx.z & 1;
    const int m0 = blockIdx.y * 128;   // o
    const int n0 = blockIdx.x * 128;   // l

    const u16* A  = Wb + ((size_t)p << 20) + (size_t)m0 * CC;
    const u16* Bx = ((p == 0) ? Tt : St) + (size_t)b * LL * CC + (size_t)n0 * CC;
    const float* bias = (p == 0) ? bq : (p == 1) ? bk : bv;

    const int tid  = threadIdx.x;
    const int lane = tid & 63;
    const int wid  = tid >> 6;
    const int ln   = lane & 15;
    const int q    = lane >> 4;
    const int wm   = (wid >> 1) * 64;
    const int wn   = (wid & 1) * 64;

    // write-side inverse mapping for this thread's two slots (tid, tid+256)
    int row1, c1, row2, c2;
    { const int s = tid;       const int pp = s >> 3, j = s & 7, i = j ^ (pp & 7);
      row1 = 2 * pp + (i >> 2); c1 = i & 3; }
    { const int s = tid + 256; const int pp = s >> 3, j = s & 7, i = j ^ (pp & 7);
      row2 = 2 * pp + (i >> 2); c2 = i & 3; }
    const u16* ag1 = A  + (size_t)row1 * CC + c1 * 8;
    const u16* ag2 = A  + (size_t)row2 * CC + c2 * 8;
    const u16* bg1 = Bx + (size_t)row1 * CC + c1 * 8;
    const u16* bg2 = Bx + (size_t)row2 * CC + c2 * 8;
    const int lb = wid * 512;   // wave-uniform u16 LDS base (64 slots * 8 u16)

#define QSTAGE(buf, k0) do {                                  \
        gload_lds16(ag1 + (k0), &As[buf][lb]);                \
        gload_lds16(ag2 + (k0), &As[buf][2048 + lb]);         \
        gload_lds16(bg1 + (k0), &Bs[buf][lb]);                \
        gload_lds16(bg2 + (k0), &Bs[buf][2048 + lb]);         \
    } while (0)

    f32x4 acc[4][4];
#pragma unroll
    for (int i = 0; i < 4; i++)
#pragma unroll
        for (int j = 0; j < 4; j++) acc[i][j] = (f32x4){0.f, 0.f, 0.f, 0.f};

    // read-side lane offset: row = R + ln (R mult of 16), k-chunk = q
    // slot = (R/2 + (ln>>1))*8 + ((4*(ln&1)+q) ^ (ln>>1))  -> u16 = R*32 + loff
    const int loff = (ln >> 1) * 64 + (((((ln & 1) << 2) | q)) ^ (ln >> 1)) * 8;

    QSTAGE(0, 0);   // prologue

    int cur = 0;
    for (int k0 = 0; k0 < CC; k0 += 32) {
        __syncthreads();                       // vmcnt(0): staged buf[cur] visible
        if (k0 + 32 < CC) QSTAGE(cur ^ 1, k0 + 32);

        short8 aF[4], bF[4];
#pragma unroll
        for (int mt = 0; mt < 4; mt++)
            aF[mt] = *(const short8*)(&As[cur][wm * 32 + mt * 512 + loff]);
#pragma unroll
        for (int nt = 0; nt < 4; nt++)
            bF[nt] = *(const short8*)(&Bs[cur][wn * 32 + nt * 512 + loff]);
#pragma unroll
        for (int mt = 0; mt < 4; mt++)
#pragma unroll
            for (int nt = 0; nt < 4; nt++)
                acc[mt][nt] = __builtin_amdgcn_mfma_f32_16x16x32_bf16(aF[mt], bF[nt], acc[mt][nt], 0, 0, 0);
        cur ^= 1;
    }
#undef QSTAGE

    // Q folds 1/sqrt(DH)*log2e and tmask (zeroed rows -> uniform softmax in attn)
    const float oscale = (p == 0) ? 0.18033688011112042f : 1.0f;
    // D layout: col = lane&15 (= l), row = q*4+reg (= o)
#pragma unroll
    for (int mt = 0; mt < 4; mt++) {
        const int o_base = m0 + wm + mt * 16 + q * 4;
        float bsf[4];
#pragma unroll
        for (int r = 0; r < 4; r++) bsf[r] = bias[o_base + r];
#pragma unroll
        for (int nt = 0; nt < 4; nt++) {
            const int l = n0 + wn + nt * 16 + ln;
            if (p == 2) {
#pragma unroll
                for (int r = 0; r < 4; r++)
                    Vb[((size_t)b * CC + o_base + r) * SS + l] = f2bf(acc[mt][nt][r] + bsf[r]);
            } else {
                const int h = o_base >> 6;
                const int d = o_base & 63;
                u16* dst = (p == 0) ? Qb : Kb;
                float sc2 = oscale;
                if (p == 0) sc2 = oscale * tmaskp[(size_t)b * TT + l];
                us4 pk;
#pragma unroll
                for (int r = 0; r < 4; r++) pk[r] = (u16)f2bf((acc[mt][nt][r] + bsf[r]) * sc2);
                *(us4*)(dst + ((size_t)(b * HH + h) * TT + l) * 64 + d) = pk;
            }
        }
    }
}

// ---------- flash attention (round-2 structure + T5 setprio around MFMA clusters) ----------
__global__ __launch_bounds__(256, 4) void attn_k(
    const u16* __restrict__ Qb, const u16* __restrict__ Kb, const u16* __restrict__ Vb,
    const float* __restrict__ tmask, const float* __restrict__ sbias,
    const float* __restrict__ zrow, float* __restrict__ out)
{
    __shared__ __align__(16) u16 Ks[2][64 * 64];   // [s_local][d], 16B-chunk col ^= (row&7)
    __shared__ __align__(16) u16 Vs[2][64 * 64];   // [d][s_local], same swizzle
    __shared__ __align__(16) u16 Ps[4][16 * 64];   // per-wave P^T [t_local][s_local]

    const int tid  = threadIdx.x;
    const int wid  = tid >> 6;
    const int lane = tid & 63;
    const int ln   = lane & 15;
    const int q    = lane >> 4;

    const int idx   = blockIdx.x;
    const int xcd   = idx & 7;
    const int rest  = idx >> 3;
    const int ttile = rest & 31;
    const int bh    = (rest >> 5) * 8 + xcd;   // 0..31
    const int b     = bh >> 4;
    const int h     = bh & 15;
    const int t0    = ttile * 64 + wid * 16;

    const u16* Qp = Qb + (size_t)bh * TT * 64;
    const u16* Kp = Kb + (size_t)bh * SS * 64;
    const u16* Vp = Vb + ((size_t)b * CC + h * 64) * SS;

    const float tm = tmask[(size_t)b * TT + t0 + ln];
    const float* bp = (tm > 0.5f) ? (sbias + (size_t)b * SS) : zrow;

    const int r0  = tid >> 3;
    const int c0  = tid & 7;
    const int cs0 = c0 ^ (r0 & 7);
    const u16* kg0 = Kp + (size_t)r0 * 64 + cs0 * 8;
    const u16* kg1 = Kp + (size_t)(r0 + 32) * 64 + cs0 * 8;
    const u16* vg0 = Vp + (size_t)r0 * SS + cs0 * 8;
    const u16* vg1 = Vp + (size_t)(r0 + 32) * SS + cs0 * 8;
    const int lw0 = wid * 512;
    const int lw1 = 2048 + wid * 512;

#define STAGE(buf, sn) do {                                         \
        gload_lds16(kg0 + (size_t)(sn) * 64, &Ks[buf][lw0]);        \
        gload_lds16(kg1 + (size_t)(sn) * 64, &Ks[buf][lw1]);        \
        gload_lds16(vg0 + (sn), &Vs[buf][lw0]);                     \
        gload_lds16(vg1 + (sn), &Vs[buf][lw1]);                     \
    } while (0)

    short8 qB0 = *(const short8*)(Qp + (size_t)(t0 + ln) * 64 + q * 8);
    short8 qB1 = *(const short8*)(Qp + (size_t)(t0 + ln) * 64 + 32 + q * 8);

    float mR = -3.0e38f, lR = 0.f;
    f32x4 oA[4];
#pragma unroll
    for (int dt = 0; dt < 4; dt++) oA[dt] = (f32x4){0.f, 0.f, 0.f, 0.f};

    const int sx0 = ((q ^ (ln & 7)) << 3);
    const int sx1 = (((q + 4) ^ (ln & 7)) << 3);

    u16* pw = Ps[wid];

    STAGE(0, 0);

    int cur = 0;
#pragma unroll 2
    for (int it = 0; it < NT_TILES; ++it) {
        const int s0 = it * 64;
        __syncthreads();
        if (it + 1 < NT_TILES) STAGE(cur ^ 1, s0 + 64);

        const u16* KsB = Ks[cur];
        const u16* VsB = Vs[cur];

        f32x4 sc[4];
        __builtin_amdgcn_s_setprio(1);
#pragma unroll
        for (int nt = 0; nt < 4; nt++) {
            const u16* kr = KsB + (nt * 16 + ln) * 64;
            short8 k0 = *(const short8*)(kr + sx0);
            short8 k1 = *(const short8*)(kr + sx1);
            f32x4 bias = *(const f32x4*)(bp + s0 + nt * 16 + q * 4);
            sc[nt] = __builtin_amdgcn_mfma_f32_16x16x32_bf16(k0, qB0, bias, 0, 0, 0);
            sc[nt] = __builtin_amdgcn_mfma_f32_16x16x32_bf16(k1, qB1, sc[nt], 0, 0, 0);
        }
        __builtin_amdgcn_s_setprio(0);

        float m4[4];
#pragma unroll
        for (int nt = 0; nt < 4; nt++)
            m4[nt] = fmaxf(max3f(sc[nt][0], sc[nt][1], sc[nt][2]), sc[nt][3]);
        float m_ = fmaxf(max3f(m4[0], m4[1], m4[2]), m4[3]);
        m_ = fmaxf(m_, __shfl_xor(m_, 16, 64));
        m_ = fmaxf(m_, __shfl_xor(m_, 32, 64));

        if (!__all(m_ - mR <= 8.0f)) {
            const float mN = fmaxf(mR, m_);
            const float al = exp2_hw(mR - mN);
            lR *= al;
#pragma unroll
            for (int dt = 0; dt < 4; dt++) oA[dt] *= al;
            mR = mN;
        }

        float s4[4];
#pragma unroll
        for (int nt = 0; nt < 4; nt++) {
#pragma unroll
            for (int r = 0; r < 4; r++) sc[nt][r] = exp2_hw(sc[nt][r] - mR);
            s4[nt] = (sc[nt][0] + sc[nt][1]) + (sc[nt][2] + sc[nt][3]);
        }
        float s_ = (s4[0] + s4[1]) + (s4[2] + s4[3]);
        s_ += __shfl_xor(s_, 16, 64);
        s_ += __shfl_xor(s_, 32, 64);
        lR += s_;

#pragma unroll
        for (int nt = 0; nt < 4; nt++) {
            u32x2 w;
            w[0] = cvtpk_bf16(sc[nt][0], sc[nt][1]);
            w[1] = cvtpk_bf16(sc[nt][2], sc[nt][3]);
            const int chunk = (nt << 1) | (q >> 1);
            *(u32x2*)(pw + ln * 64 + ((chunk ^ (ln & 7)) << 3) + ((q & 1) << 2)) = w;
        }
        short8 pB0 = *(const short8*)(pw + ln * 64 + sx0);
        short8 pB1 = *(const short8*)(pw + ln * 64 + sx1);
        __builtin_amdgcn_s_setprio(1);
#pragma unroll
        for (int dt = 0; dt < 4; dt++) {
            const u16* vr = VsB + (dt * 16 + ln) * 64;
            short8 v0 = *(const short8*)(vr + sx0);
            short8 v1 = *(const short8*)(vr + sx1);
            oA[dt] = __builtin_amdgcn_mfma_f32_16x16x32_bf16(v0, pB0, oA[dt], 0, 0, 0);
            oA[dt] = __builtin_amdgcn_mfma_f32_16x16x32_bf16(v1, pB1, oA[dt], 0, 0, 0);
        }
        __builtin_amdgcn_s_setprio(0);
        cur ^= 1;
    }
#undef STAGE

    const float inv = 1.0f / lR;
#pragma unroll
    for (int dt = 0; dt < 4; dt++)
#pragma unroll
        for (int r = 0; r < 4; r++)
            out[((size_t)b * CC + h * 64 + dt * 16 + q * 4 + r) * TT + t0 + ln] =
                oA[dt][r] * inv;
}

extern "C" void kernel_launch(void* const* d_in, const int* in_sizes, int n_in,
                              void* d_out, int out_size, void* d_ws, size_t ws_size,
                              hipStream_t stream)
{
    const float* target = (const float*)d_in[0];
    const float* source = (const float*)d_in[1];
    const float* tmask  = (const float*)d_in[2];
    const float* smask  = (const float*)d_in[3];
    const float* Wq = (const float*)d_in[4];
    const float* bq = (const float*)d_in[5];
    const float* Wk = (const float*)d_in[6];
    const float* bk = (const float*)d_in[7];
    const float* Wv = (const float*)d_in[8];
    const float* bv = (const float*)d_in[9];

    u16* ws = (u16*)d_ws;
    const size_t N1 = (size_t)BB * CC * TT;   // 4,194,304 elements (8 MB bf16)
    u16* Qb = ws;
    u16* Kb = ws + N1;
    u16* Vb = ws + 2 * N1;                    // 24 MB bf16
    float* sbias = (float*)(ws + 3 * N1);     // [2][2048] f32
    float* zrow  = sbias + 2 * SS;            // [2048] f32
    u16* Wb = (u16*)(zrow + SS);              // [3][1024][1024] bf16, 6 MB
    u16* Tt = Wb + 3u * 1048576u;             // [2][2048][1024] bf16, 8 MB
    u16* St = Tt + (size_t)BB * LL * CC;      // [2][2048][1024] bf16, 8 MB

    prep<<<dim3(3584, 1, 1), dim3(256, 1, 1), 0, stream>>>(
        target, source, smask, Wq, Wk, Wv, Wb, Tt, St, sbias, zrow);
    qkv_gemm<<<dim3(TT/128, CC/128, 6), dim3(256, 1, 1), 0, stream>>>(
        Wb, Tt, St, bq, bk, bv, tmask, Qb, Kb, Vb);
    attn_k<<<dim3(BB*HH*(TT/64), 1, 1), dim3(256, 1, 1), 0, stream>>>(
        Qb, Kb, Vb, tmask, sbias, zrow, (float*)d_out);
}